// Round 5
// baseline (346.418 us; speedup 1.0000x reference)
//
#include <hip/hip_runtime.h>

// ApsUp: polyphase 2x upsample (per-batch phase) + circular pad + depthwise
// 3x3 binomial blur, fused into a single gather kernel.
//
// v6 — DIAGNOSTIC ROUND (intentionally slower, correctness identical).
//   v2/v3/v5 (one-shot waves, contiguous plain stores, 8x-deep loops) all
//   landed within +-5 us total; the kernel's own counters have never been
//   visible (poison fills dominate top-5). This version runs the SAME v3
//   computation 4x in-kernel (idempotent rewrites, asm memory fences stop
//   dead-store elimination) so the dispatch exceeds the ~167 us fills and
//   surfaces its own FETCH/WRITE/hbm_gbps/VALUBusy/Occupancy row, and so
//   row_dur/4 gives the true per-pass time (removing the subtraction
//   ambiguity vs hidden fixed harness costs).
//
// Per-pass math (v3): thread owns input rows k,k+1 (float2 cols 2j4,2j4+1):
//   s(u=2k) = 2*row_k ; s(u=2k+1) = row_k + row_{k+1}
//   horizontal [1,2,1] via in-thread sums + one __shfl edge element,
//   2 full-line float4 stores to output rows 2k+r, 2k+1+r.

typedef float v4f __attribute__((ext_vector_type(4)));
typedef float v2f __attribute__((ext_vector_type(2)));

__global__ __launch_bounds__(256) void aps_up_kernel(
    const float* __restrict__ inp,     // [16,256,64,64]
    const int*   __restrict__ phase,   // [16]
    float*       __restrict__ out)     // [16,256,128,128]
{
    const int g = blockIdx.x * 256 + threadIdx.x;  // thread = 2 output float4s

    const int j4    = g & 31;          // float2-col (32 per 64-col input row)
    const int k     = (g >> 5) & 63;   // input row pair (u = 2k, 2k+1)
    const int plane = g >> 11;         // b*256 + ch (8 blocks/plane, no straddle)

    const int p = phase[blockIdx.x >> 11];   // block-uniform scalar load
    const int r = p & 1;
    const int c = p >> 1;

    const v2f* basef2 = reinterpret_cast<const v2f*>(inp) + (size_t)plane * 2048;
    v4f*       outp   = reinterpret_cast<v4f*>(out)       + (size_t)plane * 4096;

    const int grp  = threadIdx.x & 32;       // 32-lane row-group base
    const int srcN = grp | ((j4 + 1) & 31);  // next lane (col wrap 63->0)
    const int srcP = grp | ((j4 - 1) & 31);  // prev lane (col wrap 0->63)

    const int rowA = ((2 * k + r) & 127) * 32 + j4;
    const int rowB = ((2 * k + 1 + r) & 127) * 32 + j4;

    #pragma unroll 1
    for (int pass = 0; pass < 4; ++pass) {
        const v2f vk  = basef2[k * 32 + j4];
        const v2f vk1 = basef2[((k + 1) & 63) * 32 + j4];

        const v2f sA = vk + vk;        // u = 2k (row k dup, weight 2)
        const v2f sB = vk + vk1;       // u = 2k+1

        v4f oA, oB;
        if (c == 0) {
            const float nA = __shfl(sA.x, srcN, 64);
            const float nB = __shfl(sB.x, srcN, 64);
            oA = (v4f){sA.x + sA.x, sA.x + sA.y, sA.y + sA.y, sA.y + nA};
            oB = (v4f){sB.x + sB.x, sB.x + sB.y, sB.y + sB.y, sB.y + nB};
        } else {
            const float mA = __shfl(sA.y, srcP, 64);
            const float mB = __shfl(sB.y, srcP, 64);
            oA = (v4f){mA + sA.x, sA.x + sA.x, sA.x + sA.y, sA.y + sA.y};
            oB = (v4f){mB + sB.x, sB.x + sB.x, sB.x + sB.y, sB.y + sB.y};
        }
        oA *= 0.0625f;
        oB *= 0.0625f;

        outp[rowA] = oA;
        outp[rowB] = oB;

        // Fence: forbid CSE/dead-store elimination across passes so each
        // pass issues real loads and real stores (idempotent -> correct).
        asm volatile("" ::: "memory");
    }
}

extern "C" void kernel_launch(void* const* d_in, const int* in_sizes, int n_in,
                              void* d_out, int out_size, void* d_ws, size_t ws_size,
                              hipStream_t stream) {
    const float* inp   = (const float*)d_in[0];
    const int*   phase = (const int*)d_in[1];
    float*       out   = (float*)d_out;

    // out_size = 16*256*128*128 floats; 8 per thread (2 float4)
    const int total_threads = out_size / 8;            // 8,388,608
    const int block = 256;
    const int grid  = total_threads / block;           // 32,768
    aps_up_kernel<<<grid, block, 0, stream>>>(inp, phase, out);
}